// Round 1
// baseline (135.743 us; speedup 1.0000x reference)
//
#include <hip/hip_runtime.h>

// LogSignature depth-4, C=16, B=64, L=256, fp32.
// out per batch: [lvl1(16) | lvl2(256) | lvl3(4096) | lvl4(65536)] = 69904
//
// v2: time-split scan (Chen). k_scan runs 2 chunks (steps 0..127 / 128..254)
// concurrently -> 2048 blocks = 8 blocks/CU = 32 waves/CU (residency cap),
// doubling latency hiding for the VALU-bound scan. k_log fuses the Chen merge
// (S4 = A4 + B4 + A3⊗B1 + A2⊗B2 + A1⊗B3; merged S1..S3 built in LDS) with the
// existing log correction at the cost of one extra 16KB read per block.
//
// ws layout (floats):
//   dx1  [j][t][i]  : 64*255*16 = 261120  (time-major, wave-uniform row loads)
//   dxt  [j][i][256]: 64*16*256 = 262144  (component-major, per-lane float4)
//   sigA [j][4368]  : levels 1-3 of chunk A (or full scan in fallback)
//   sigB [j][4368]  : levels 1-3 of chunk B
//   B4   [j][a][4096]: level-4 partial of chunk B (A4 goes directly to out L4)
// total ~21.1 MB; falls back to unsplit path if ws is smaller.

#define NC 16
#define NL 256
#define NB 64
#define NSTEP 255
#define OUTB 69904
#define SIG123 4368
#define OFF_L2 16
#define OFF_L3 272
#define OFF_L4 4368

#define DX1_OFF 0
#define DXT_OFF 261120
#define SIGA_OFF (261120 + 262144)
#define SIGB_OFF (SIGA_OFF + NB * SIG123)
#define B4_OFF (SIGB_OFF + NB * SIG123)
#define WS_NEED_F ((size_t)B4_OFF + (size_t)NB * 16 * 4096)

// One block per batch j: stage path[j] (16 KB) in LDS, emit both dx layouts.
__global__ __launch_bounds__(256) void k_dx(const float* __restrict__ path,
                                            float* __restrict__ dx1,
                                            float* __restrict__ dxt) {
    const int j = blockIdx.x;
    const int tid = threadIdx.x;
    __shared__ float L[NL * NC];  // 16 KB, [t][i]

    const float* pj = path + (size_t)j * NL * NC;
#pragma unroll
    for (int k = 0; k < 4; ++k) {
        const int f = tid + k * 256;  // float4 index
        *(float4*)&L[f * 4] = *(const float4*)&pj[f * 4];
    }
    __syncthreads();

    // time-major diffs (coalesced)
    float* d1 = dx1 + (size_t)j * NSTEP * NC;
    for (int f = tid; f < NSTEP * NC; f += 256) d1[f] = L[f + NC] - L[f];

    // component-major diffs: iter k = row i, lane = t
    float* dt = dxt + (size_t)j * NC * 256;
#pragma unroll
    for (int k = 0; k < NC; ++k) {
        const int t = tid;
        if (t < NSTEP) dt[k * 256 + t] = L[(t + 1) * NC + k] - L[t * NC + k];
    }
}

// Chunk-local signature scan. Block = (j, a, half). Thread (b,c) owns
// s3[a,b,c] and s4[a,b,c,0..15] in registers; s1[a], s2[a,b] redundant.
// half 0: steps [0,128) -> A4 into out L4, A123 into sigA.
// half 1: steps [128,255) -> B4 into ws, B123 into sigB.
// split==0: single chunk [0,255) (fallback), identical to v1 behavior.
__global__ __launch_bounds__(256, 8) void k_scan(const float* __restrict__ dx1,
                                                 const float* __restrict__ dxt,
                                                 float* __restrict__ out,
                                                 float* __restrict__ b4,
                                                 float* __restrict__ sigA,
                                                 float* __restrict__ sigB,
                                                 const int split) {
    int bid = blockIdx.x;
    int h = 0;
    if (split) { h = bid & 1; bid >>= 1; }
    const int j = bid >> 4;
    const int a = bid & 15;
    const int tid = threadIdx.x;
    const int b = tid >> 4;
    const int c = tid & 15;

    const int t0 = h ? 128 : 0;
    const int t1 = (split && !h) ? 128 : NSTEP;

    float s4[16];
#pragma unroll
    for (int d = 0; d < 16; ++d) s4[d] = 0.f;
    float s3 = 0.f, s2ab = 0.f, s1a = 0.f;

    const float* row0 = dx1 + (size_t)j * NSTEP * NC;    // [t][16], uniform
    const float* ra = dxt + ((size_t)j * NC + a) * 256;  // uniform
    const float* rb = dxt + ((size_t)j * NC + b) * 256;  // per-lane stream
    const float* rc = dxt + ((size_t)j * NC + c) * 256;

    int t = t0;
    const int nv = (t1 - t0) >> 2;
    for (int it = 0; it < nv; ++it, t += 4) {
        const float4 vb = *(const float4*)(rb + t);  // 4 steps of dxb
        const float4 vc = *(const float4*)(rc + t);
        const float4 va = *(const float4*)(ra + t);  // uniform -> scalar load
#pragma unroll
        for (int u = 0; u < 4; ++u) {
            const float* r = row0 + (t + u) * NC;  // uniform row
            const float4 q0 = *(const float4*)(r);
            const float4 q1 = *(const float4*)(r + 4);
            const float4 q2 = *(const float4*)(r + 8);
            const float4 q3 = *(const float4*)(r + 12);
            const float dxa = (u == 0) ? va.x : (u == 1) ? va.y : (u == 2) ? va.z : va.w;
            const float dxb = (u == 0) ? vb.x : (u == 1) ? vb.y : (u == 2) ? vb.z : vb.w;
            const float dxc = (u == 0) ? vc.x : (u == 1) ? vc.y : (u == 2) ? vc.z : vc.w;

            const float pre4 = fmaf(dxb, fmaf(1.f / 6.f, s1a, (1.f / 24.f) * dxa), 0.5f * s2ab);
            const float T = fmaf(dxc, pre4, s3);
            const float dv[16] = {q0.x, q0.y, q0.z, q0.w, q1.x, q1.y, q1.z, q1.w,
                                  q2.x, q2.y, q2.z, q2.w, q3.x, q3.y, q3.z, q3.w};
#pragma unroll
            for (int d = 0; d < 16; ++d) s4[d] = fmaf(dv[d], T, s4[d]);

            const float U = fmaf(dxb, fmaf(0.5f, s1a, (1.f / 6.f) * dxa), s2ab);
            s3 = fmaf(dxc, U, s3);
            s2ab = fmaf(dxb, fmaf(0.5f, dxa, s1a), s2ab);
            s1a += dxa;
        }
    }
    // tail (only the last chunk has one: 252..254)
    for (; t < t1; ++t) {
        const float* r = row0 + t * NC;
        const float4 q0 = *(const float4*)(r);
        const float4 q1 = *(const float4*)(r + 4);
        const float4 q2 = *(const float4*)(r + 8);
        const float4 q3 = *(const float4*)(r + 12);
        const float dxa = ra[t];
        const float dxb = rb[t];
        const float dxc = rc[t];
        const float pre4 = fmaf(dxb, fmaf(1.f / 6.f, s1a, (1.f / 24.f) * dxa), 0.5f * s2ab);
        const float T = fmaf(dxc, pre4, s3);
        const float dv[16] = {q0.x, q0.y, q0.z, q0.w, q1.x, q1.y, q1.z, q1.w,
                              q2.x, q2.y, q2.z, q2.w, q3.x, q3.y, q3.z, q3.w};
#pragma unroll
        for (int d = 0; d < 16; ++d) s4[d] = fmaf(dv[d], T, s4[d]);
        const float U = fmaf(dxb, fmaf(0.5f, s1a, (1.f / 6.f) * dxa), s2ab);
        s3 = fmaf(dxc, U, s3);
        s2ab = fmaf(dxb, fmaf(0.5f, dxa, s1a), s2ab);
        s1a += dxa;
    }

    // epilogue: stage s4 slice in LDS, write block's contiguous 16 KB coalesced
    __shared__ float ls[4096];
#pragma unroll
    for (int d = 0; d < 16; d += 4)
        *(float4*)&ls[tid * 16 + d] = make_float4(s4[d], s4[d + 1], s4[d + 2], s4[d + 3]);
    __syncthreads();

    float* o4 = h ? (b4 + (((size_t)j * 16 + a) << 12))
                  : (out + (size_t)j * OUTB + OFF_L4 + a * 4096);
#pragma unroll
    for (int k = 0; k < 4; ++k) {
        const int f = tid + k * 256;  // float4 index 0..1023
        *(float4*)(o4 + f * 4) = *(const float4*)&ls[f * 4];
    }

    float* sg = (h ? sigB : sigA) + (size_t)j * SIG123;
    sg[OFF_L3 + (a * 16 + b) * 16 + c] = s3;
    if (c == 0) sg[OFF_L2 + a * 16 + b] = s2ab;
    if (tid == 0) sg[a] = s1a;
}

// Chen merge (A ⊗ B, A = first chunk taking leading indices) + log correction.
// Block (j,a). Merged S1/S2/S3 and B1/B2/B3 staged in LDS (36 KB).
// mscale = 0 -> B treated as identity (fallback == v1 k_log semantics).
__global__ __launch_bounds__(256) void k_log(const float* __restrict__ sigA,
                                             const float* __restrict__ sigB,
                                             const float* __restrict__ b4,
                                             float* __restrict__ out,
                                             const float mscale) {
    const int bid = blockIdx.x;
    const int j = bid >> 4;
    const int a = bid & 15;
    const int tid = threadIdx.x;
    const int q = tid >> 4;  // second index of (p,q,r) triples below
    const int r = tid & 15;

    const float* A = sigA + (size_t)j * SIG123;
    const float* Bp = sigB + (size_t)j * SIG123;

    __shared__ float S1m[16], B1s[16], A2s[16];
    __shared__ float S2m[256], B2s[256], A3s[256];
    __shared__ float S3m[4096], B3s[4096];

    const float b1r = mscale * Bp[r];             // B1[r]
    const float b2t = mscale * Bp[OFF_L2 + tid];  // B2[q,r]

    if (tid < 16) {
        const float bb = mscale * Bp[tid];
        B1s[tid] = bb;
        S1m[tid] = A[tid] + bb;                  // S1 = A1 + B1
        A2s[tid] = A[OFF_L2 + a * 16 + tid];     // A2[a,:]
    }
    B2s[tid] = b2t;
    S2m[tid] = A[OFF_L2 + tid] + b2t + A[q] * b1r;  // S2 = A2 + B2 + A1⊗B1
    A3s[tid] = A[OFF_L3 + a * 256 + tid];           // A3[a,:,:]
#pragma unroll
    for (int k = 0; k < 16; ++k) {  // S3[p=k,q,r] = A3 + B3 + A1[p]B2[qr] + A2[pq]B1[r]
        const int m = k * 256 + tid;
        const float b3 = mscale * Bp[OFF_L3 + m];
        B3s[m] = b3;
        S3m[m] = A[OFF_L3 + m] + b3 + A[k] * b2t + A[OFF_L2 + k * 16 + q] * b1r;
    }
    __syncthreads();

    const float s1a = S1m[a];
    const float A1a = A[a];
    const bool mg = (mscale != 0.f);
    float* outj = out + (size_t)j * OUTB;
    float* o4 = outj + OFF_L4 + a * 4096;
    const float* B4 = b4 + (((size_t)j * 16 + a) << 12);
    const float Ac = -0.5f * s1a;

#pragma unroll
    for (int k = 0; k < 4; ++k) {
        const int f = tid + k * 256;
        const int m0 = f * 4;          // element offset: b*256 + c*16 + d0
        const int bb = m0 >> 8;
        const int cc = (m0 >> 4) & 15;
        const float s1b = S1m[bb], s1c = S1m[cc];
        const float s2ab = S2m[a * 16 + bb];
        const float s2bc = S2m[bb * 16 + cc];
        const float s3abc = S3m[a * 256 + (m0 >> 4)];  // merged S3[a,b,c]
        const float a3x = A3s[m0 >> 4];                // A3[a,b,c] (cross term)
        const float a2x = A2s[bb];                     // A2[a,b]

        const float4 a4 = *(const float4*)(o4 + m0);
        float4 b4v = make_float4(0.f, 0.f, 0.f, 0.f);
        if (mg) b4v = *(const float4*)(B4 + m0);
        const float4 b3v = *(const float4*)(&B3s[m0]);        // B3[b,c,d..]
        const float4 b2v = *(const float4*)(&B2s[m0 & 255]);  // B2[c,d..]
        const float4 b1v = *(const float4*)(&B1s[m0 & 15]);   // B1[d..]
        const float4 v3 = *(const float4*)(&S3m[m0]);         // S3[b,c,d..]
        const float4 v2 = *(const float4*)(&S2m[m0 & 255]);   // S2[c,d..]
        const float4 v1 = *(const float4*)(&S1m[m0 & 15]);    // S1[d..]

        const float Bv = fmaf((1.f / 3.f) * s1a, s1b, -0.5f * s2ab);
        const float Cv = -0.5f * s3abc + (1.f / 3.f) * fmaf(s1a, s2bc, s2ab * s1c)
                         - 0.25f * s1a * s1b * s1c;
        float4 rr;
        // merged S4 = A4 + B4 + A1[a]B3[bcd] + A2[ab]B2[cd] + A3[abc]B1[d]
        rr.x = a4.x + b4v.x + fmaf(A1a, b3v.x, fmaf(a2x, b2v.x, a3x * b1v.x));
        rr.y = a4.y + b4v.y + fmaf(A1a, b3v.y, fmaf(a2x, b2v.y, a3x * b1v.y));
        rr.z = a4.z + b4v.z + fmaf(A1a, b3v.z, fmaf(a2x, b2v.z, a3x * b1v.z));
        rr.w = a4.w + b4v.w + fmaf(A1a, b3v.w, fmaf(a2x, b2v.w, a3x * b1v.w));
        // log correction
        rr.x = fmaf(Ac, v3.x, rr.x) + fmaf(Bv, v2.x, Cv * v1.x);
        rr.y = fmaf(Ac, v3.y, rr.y) + fmaf(Bv, v2.y, Cv * v1.y);
        rr.z = fmaf(Ac, v3.z, rr.z) + fmaf(Bv, v2.z, Cv * v1.z);
        rr.w = fmaf(Ac, v3.w, rr.w) + fmaf(Bv, v2.w, Cv * v1.w);
        *(float4*)(o4 + m0) = rr;
    }

    // level 3 (coalesced)
    {
        const float s1b = S1m[q], s1c = S1m[r];
        const float s2ab = S2m[a * 16 + q];
        const float s2bc = S2m[q * 16 + r];
        const float s3abc = S3m[a * 256 + tid];
        const float r3 = s3abc - 0.5f * fmaf(s1a, s2bc, s2ab * s1c)
                         + (1.f / 3.f) * s1a * s1b * s1c;
        outj[OFF_L3 + a * 256 + tid] = r3;
    }
    // level 2
    if (tid < 16) outj[OFF_L2 + a * 16 + tid] = fmaf(-0.5f * s1a, S1m[tid], S2m[a * 16 + tid]);
    // level 1
    if (tid == 0) outj[a] = s1a;
}

extern "C" void kernel_launch(void* const* d_in, const int* in_sizes, int n_in,
                              void* d_out, int out_size, void* d_ws, size_t ws_size,
                              hipStream_t stream) {
    const float* path = (const float*)d_in[0];
    float* out = (float*)d_out;
    float* ws = (float*)d_ws;
    float* dx1 = ws + DX1_OFF;
    float* dxt = ws + DXT_OFF;
    float* sigA = ws + SIGA_OFF;

    const int split = (ws_size >= WS_NEED_F * sizeof(float)) ? 1 : 0;
    float* sigB = split ? (ws + SIGB_OFF) : sigA;
    float* b4 = split ? (ws + B4_OFF) : out;  // fallback: valid reads, scaled x0

    k_dx<<<NB, 256, 0, stream>>>(path, dx1, dxt);
    k_scan<<<split ? NB * 32 : NB * 16, 256, 0, stream>>>(dx1, dxt, out, b4, sigA, sigB, split);
    k_log<<<NB * 16, 256, 0, stream>>>(sigA, sigB, b4, out, split ? 1.f : 0.f);
}

// Round 2
// 113.299 us; speedup vs baseline: 1.1981x; 1.1981x over previous
//
#include <hip/hip_runtime.h>

// LogSignature depth-4, C=16, B=64, L=256, fp32.
// out per batch: [lvl1(16) | lvl2(256) | lvl3(4096) | lvl4(65536)] = 69904
//
// v3: two kernels.
// k_scan: block (j,a), 256 threads = {half(1b) | b(4b) | c0(3b)}. Each thread
// owns TWO c-values (c0, c0+8), sharing the (a,b)-only recurrence chain
// (s1a/s2ab/pre4/U) and all loads across both -> ~18% fewer VALU ops and 2x
// fewer loads per output unit. Time-split (Chen) lives inside the block:
// half 0 scans steps [0,128), half 1 scans [128,255). All dx data is staged
// and differenced in LDS (no dxt/dx1 workspace, no k_dx kernel): rows via
// uniform ds_read_b128 broadcast, dxa/dxb/dxc via conflict-free ds_read_b32.
// k_log: Chen merge (S = A (x) B) fused with log correction (round-1
// structure, fallback removed).
//
// ws (floats): sigA [64][4368] | sigB [64][4368] | B4 [64][16][4096]  (~19 MB)

#define NC 16
#define NL 256
#define NB 64
#define NSTEP 255
#define OUTB 69904
#define SIG123 4368
#define OFF_L2 16
#define OFF_L3 272
#define OFF_L4 4368

#define SIGA_OFF 0
#define SIGB_OFF (NB * SIG123)
#define B4_OFF (2 * NB * SIG123)

__global__ __launch_bounds__(256, 4) void k_scan(const float* __restrict__ path,
                                                 float* __restrict__ out,
                                                 float* __restrict__ b4,
                                                 float* __restrict__ sigA,
                                                 float* __restrict__ sigB) {
    const int bid = blockIdx.x;
    const int j = bid >> 4;
    const int a = bid & 15;
    const int tid = threadIdx.x;
    const int h = tid >> 7;          // time chunk: 0 -> [0,128), 1 -> [128,255)
    const int b = (tid >> 3) & 15;
    const int c0 = tid & 7;          // owns c0 and c0+8

    __shared__ float Lp[NL * NC];    // path staging; reused for s4 epilogue
    __shared__ float Ld[NSTEP * NC]; // diffs, time-major [t][i]

    // stage path[j] (16 KB, coalesced)
    const float* pj = path + (size_t)j * NL * NC;
#pragma unroll
    for (int k = 0; k < 4; ++k) {
        const int f = tid + k * 256;
        *(float4*)&Lp[f * 4] = *(const float4*)&pj[f * 4];
    }
    __syncthreads();

    // diffs: Ld[t*16+i] = Lp[(t+1)*16+i] - Lp[t*16+i], vectorized
#pragma unroll
    for (int k = 0; k < 4; ++k) {
        const int f = tid + k * 256;  // float4 index
        if (f < 1020) {
            const float4 x0 = *(const float4*)&Lp[f * 4];
            const float4 x1 = *(const float4*)&Lp[f * 4 + 16];
            *(float4*)&Ld[f * 4] =
                make_float4(x1.x - x0.x, x1.y - x0.y, x1.z - x0.z, x1.w - x0.w);
        }
    }
    __syncthreads();

    float s4a[16], s4b[16];
#pragma unroll
    for (int d = 0; d < 16; ++d) { s4a[d] = 0.f; s4b[d] = 0.f; }
    float s3_0 = 0.f, s3_1 = 0.f, s2ab = 0.f, s1a = 0.f;

    const int t0 = h ? 128 : 0;
    const int t1 = h ? NSTEP : 128;

    int t = t0;
    const int nv = (t1 - t0) >> 2;
    for (int it = 0; it < nv; ++it) {
#pragma unroll
        for (int u = 0; u < 4; ++u, ++t) {
            const float* r = Ld + t * NC;
            const float4 q0 = *(const float4*)(r);       // uniform b128 broadcast
            const float4 q1 = *(const float4*)(r + 4);
            const float4 q2 = *(const float4*)(r + 8);
            const float4 q3 = *(const float4*)(r + 12);
            const float dxa = r[a];
            const float dxb = r[b];
            const float dxc0 = r[c0];
            const float dxc1 = r[c0 + 8];

            const float P = dxb * s1a;
            const float Q = dxb * dxa;
            const float pre4 = fmaf(1.f / 6.f, P, fmaf(1.f / 24.f, Q, 0.5f * s2ab));
            const float U = fmaf(0.5f, P, fmaf(1.f / 6.f, Q, s2ab));
            const float T0 = fmaf(dxc0, pre4, s3_0);
            const float T1 = fmaf(dxc1, pre4, s3_1);
            const float dv[16] = {q0.x, q0.y, q0.z, q0.w, q1.x, q1.y, q1.z, q1.w,
                                  q2.x, q2.y, q2.z, q2.w, q3.x, q3.y, q3.z, q3.w};
#pragma unroll
            for (int d = 0; d < 16; ++d) {
                s4a[d] = fmaf(dv[d], T0, s4a[d]);
                s4b[d] = fmaf(dv[d], T1, s4b[d]);
            }
            s3_0 = fmaf(dxc0, U, s3_0);
            s3_1 = fmaf(dxc1, U, s3_1);
            s2ab = fmaf(dxb, fmaf(0.5f, dxa, s1a), s2ab);
            s1a += dxa;
        }
    }
    // tail (half 1 only: t = 252..254)
    for (; t < t1; ++t) {
        const float* r = Ld + t * NC;
        const float4 q0 = *(const float4*)(r);
        const float4 q1 = *(const float4*)(r + 4);
        const float4 q2 = *(const float4*)(r + 8);
        const float4 q3 = *(const float4*)(r + 12);
        const float dxa = r[a];
        const float dxb = r[b];
        const float dxc0 = r[c0];
        const float dxc1 = r[c0 + 8];
        const float P = dxb * s1a;
        const float Q = dxb * dxa;
        const float pre4 = fmaf(1.f / 6.f, P, fmaf(1.f / 24.f, Q, 0.5f * s2ab));
        const float U = fmaf(0.5f, P, fmaf(1.f / 6.f, Q, s2ab));
        const float T0 = fmaf(dxc0, pre4, s3_0);
        const float T1 = fmaf(dxc1, pre4, s3_1);
        const float dv[16] = {q0.x, q0.y, q0.z, q0.w, q1.x, q1.y, q1.z, q1.w,
                              q2.x, q2.y, q2.z, q2.w, q3.x, q3.y, q3.z, q3.w};
#pragma unroll
        for (int d = 0; d < 16; ++d) {
            s4a[d] = fmaf(dv[d], T0, s4a[d]);
            s4b[d] = fmaf(dv[d], T1, s4b[d]);
        }
        s3_0 = fmaf(dxc0, U, s3_0);
        s3_1 = fmaf(dxc1, U, s3_1);
        s2ab = fmaf(dxb, fmaf(0.5f, dxa, s1a), s2ab);
        s1a += dxa;
    }

    __syncthreads();  // all compute done; Lp reusable as staging buffer
    float* ls = Lp;

    // chunk A level-4 -> out
    if (h == 0) {
        const int base = b * 256 + c0 * 16;
#pragma unroll
        for (int d = 0; d < 16; d += 4) {
            *(float4*)&ls[base + d] = make_float4(s4a[d], s4a[d + 1], s4a[d + 2], s4a[d + 3]);
            *(float4*)&ls[base + 128 + d] =
                make_float4(s4b[d], s4b[d + 1], s4b[d + 2], s4b[d + 3]);
        }
    }
    __syncthreads();
    {
        float* o4 = out + (size_t)j * OUTB + OFF_L4 + a * 4096;
#pragma unroll
        for (int k = 0; k < 4; ++k) {
            const int f = tid + k * 256;
            *(float4*)(o4 + f * 4) = *(const float4*)&ls[f * 4];
        }
    }
    __syncthreads();

    // chunk B level-4 -> ws
    if (h == 1) {
        const int base = b * 256 + c0 * 16;
#pragma unroll
        for (int d = 0; d < 16; d += 4) {
            *(float4*)&ls[base + d] = make_float4(s4a[d], s4a[d + 1], s4a[d + 2], s4a[d + 3]);
            *(float4*)&ls[base + 128 + d] =
                make_float4(s4b[d], s4b[d + 1], s4b[d + 2], s4b[d + 3]);
        }
    }
    __syncthreads();
    {
        float* o4 = b4 + (((size_t)j * 16 + a) << 12);
#pragma unroll
        for (int k = 0; k < 4; ++k) {
            const int f = tid + k * 256;
            *(float4*)(o4 + f * 4) = *(const float4*)&ls[f * 4];
        }
    }

    // levels 1-3 of this thread's chunk
    float* sg = (h ? sigB : sigA) + (size_t)j * SIG123;
    sg[OFF_L3 + (a * 16 + b) * 16 + c0] = s3_0;
    sg[OFF_L3 + (a * 16 + b) * 16 + c0 + 8] = s3_1;
    if (c0 == 0) sg[OFF_L2 + a * 16 + b] = s2ab;
    if ((tid & 127) == 0) sg[a] = s1a;
}

// Chen merge (A (x) B, A = first chunk taking leading indices) + log correction.
// Block (j,a). Merged S1/S2/S3 and B1/B2/B3 staged in LDS (~35 KB).
__global__ __launch_bounds__(256) void k_log(const float* __restrict__ sigA,
                                             const float* __restrict__ sigB,
                                             const float* __restrict__ b4,
                                             float* __restrict__ out) {
    const int bid = blockIdx.x;
    const int j = bid >> 4;
    const int a = bid & 15;
    const int tid = threadIdx.x;
    const int q = tid >> 4;
    const int r = tid & 15;

    const float* A = sigA + (size_t)j * SIG123;
    const float* Bp = sigB + (size_t)j * SIG123;

    __shared__ float S1m[16], B1s[16], A2s[16];
    __shared__ float S2m[256], B2s[256], A3s[256];
    __shared__ float S3m[4096], B3s[4096];

    const float b1r = Bp[r];             // B1[r]
    const float b2t = Bp[OFF_L2 + tid];  // B2[q,r]

    if (tid < 16) {
        const float bb = Bp[tid];
        B1s[tid] = bb;
        S1m[tid] = A[tid] + bb;               // S1 = A1 + B1
        A2s[tid] = A[OFF_L2 + a * 16 + tid];  // A2[a,:]
    }
    B2s[tid] = b2t;
    S2m[tid] = A[OFF_L2 + tid] + b2t + A[q] * b1r;  // S2 = A2 + B2 + A1(x)B1
    A3s[tid] = A[OFF_L3 + a * 256 + tid];           // A3[a,:,:]
#pragma unroll
    for (int k = 0; k < 16; ++k) {  // S3[p=k,q,r] = A3 + B3 + A1[p]B2[qr] + A2[pq]B1[r]
        const int m = k * 256 + tid;
        const float b3 = Bp[OFF_L3 + m];
        B3s[m] = b3;
        S3m[m] = A[OFF_L3 + m] + b3 + A[k] * b2t + A[OFF_L2 + k * 16 + q] * b1r;
    }
    __syncthreads();

    const float s1a = S1m[a];
    const float A1a = A[a];
    float* outj = out + (size_t)j * OUTB;
    float* o4 = outj + OFF_L4 + a * 4096;
    const float* B4 = b4 + (((size_t)j * 16 + a) << 12);
    const float Ac = -0.5f * s1a;

#pragma unroll
    for (int k = 0; k < 4; ++k) {
        const int f = tid + k * 256;
        const int m0 = f * 4;  // element offset: b*256 + c*16 + d0
        const int bb = m0 >> 8;
        const int cc = (m0 >> 4) & 15;
        const float s1b = S1m[bb], s1c = S1m[cc];
        const float s2ab = S2m[a * 16 + bb];
        const float s2bc = S2m[bb * 16 + cc];
        const float s3abc = S3m[a * 256 + (m0 >> 4)];  // merged S3[a,b,c]
        const float a3x = A3s[m0 >> 4];                // A3[a,b,c]
        const float a2x = A2s[bb];                     // A2[a,b]

        const float4 a4 = *(const float4*)(o4 + m0);
        const float4 b4v = *(const float4*)(B4 + m0);
        const float4 b3v = *(const float4*)(&B3s[m0]);
        const float4 b2v = *(const float4*)(&B2s[m0 & 255]);
        const float4 b1v = *(const float4*)(&B1s[m0 & 15]);
        const float4 v3 = *(const float4*)(&S3m[m0]);
        const float4 v2 = *(const float4*)(&S2m[m0 & 255]);
        const float4 v1 = *(const float4*)(&S1m[m0 & 15]);

        const float Bv = fmaf((1.f / 3.f) * s1a, s1b, -0.5f * s2ab);
        const float Cv = -0.5f * s3abc + (1.f / 3.f) * fmaf(s1a, s2bc, s2ab * s1c)
                         - 0.25f * s1a * s1b * s1c;
        float4 rr;
        // merged S4 = A4 + B4 + A1[a]B3[bcd] + A2[ab]B2[cd] + A3[abc]B1[d]
        rr.x = a4.x + b4v.x + fmaf(A1a, b3v.x, fmaf(a2x, b2v.x, a3x * b1v.x));
        rr.y = a4.y + b4v.y + fmaf(A1a, b3v.y, fmaf(a2x, b2v.y, a3x * b1v.y));
        rr.z = a4.z + b4v.z + fmaf(A1a, b3v.z, fmaf(a2x, b2v.z, a3x * b1v.z));
        rr.w = a4.w + b4v.w + fmaf(A1a, b3v.w, fmaf(a2x, b2v.w, a3x * b1v.w));
        // log correction
        rr.x = fmaf(Ac, v3.x, rr.x) + fmaf(Bv, v2.x, Cv * v1.x);
        rr.y = fmaf(Ac, v3.y, rr.y) + fmaf(Bv, v2.y, Cv * v1.y);
        rr.z = fmaf(Ac, v3.z, rr.z) + fmaf(Bv, v2.z, Cv * v1.z);
        rr.w = fmaf(Ac, v3.w, rr.w) + fmaf(Bv, v2.w, Cv * v1.w);
        *(float4*)(o4 + m0) = rr;
    }

    // level 3 (coalesced)
    {
        const float s1b = S1m[q], s1c = S1m[r];
        const float s2ab = S2m[a * 16 + q];
        const float s2bc = S2m[q * 16 + r];
        const float s3abc = S3m[a * 256 + tid];
        const float r3 = s3abc - 0.5f * fmaf(s1a, s2bc, s2ab * s1c)
                         + (1.f / 3.f) * s1a * s1b * s1c;
        outj[OFF_L3 + a * 256 + tid] = r3;
    }
    // level 2
    if (tid < 16) outj[OFF_L2 + a * 16 + tid] = fmaf(-0.5f * s1a, S1m[tid], S2m[a * 16 + tid]);
    // level 1
    if (tid == 0) outj[a] = s1a;
}

extern "C" void kernel_launch(void* const* d_in, const int* in_sizes, int n_in,
                              void* d_out, int out_size, void* d_ws, size_t ws_size,
                              hipStream_t stream) {
    const float* path = (const float*)d_in[0];
    float* out = (float*)d_out;
    float* ws = (float*)d_ws;
    float* sigA = ws + SIGA_OFF;
    float* sigB = ws + SIGB_OFF;
    float* b4 = ws + B4_OFF;

    k_scan<<<NB * 16, 256, 0, stream>>>(path, out, b4, sigA, sigB);
    k_log<<<NB * 16, 256, 0, stream>>>(sigA, sigB, b4, out);
}

// Round 3
// 109.326 us; speedup vs baseline: 1.2416x; 1.0363x over previous
//
#include <hip/hip_runtime.h>

// LogSignature depth-4, C=16, B=64, L=256, fp32.
// out per batch: [lvl1(16) | lvl2(256) | lvl3(4096) | lvl4(65536)] = 69904
//
// v4:
// k_scan: block (j,a), 256 threads = {half(1b) | b(4b) | c0(3b)}, c-pair
// (c0, c0+8) per thread, in-block time split (Chen) as v3. New:
//  - dual LDS layout: Lp time-major diffs (in-place) for uniform b128 row
//    broadcasts; Lc component-major (stride 260, conflict-free) so
//    dxa/dxb/dxc0/dxc1 load as 1 b128 per 4 steps each (DS ops per 4 steps
//    32 -> 20; the LDS pipe was the co-bottleneck at VALUBusy=58%).
//  - epilogue merges A4+B4 in LDS (same block!) and writes ONE 16KB slice:
//    halves k_scan's global writes and removes k_log's B4 read entirely.
// k_log: Chen cross-terms + log correction. B3 read from L2-resident global
// (no B3s LDS) -> ~20KB LDS, 8 blocks/CU.
//
// ws (floats): sigA [64][4368] | sigB [64][4368]   (~2.2 MB)

#define NC 16
#define NL 256
#define NB 64
#define NSTEP 255
#define OUTB 69904
#define SIG123 4368
#define OFF_L2 16
#define OFF_L3 272
#define OFF_L4 4368

#define SIGA_OFF 0
#define SIGB_OFF (NB * SIG123)

#define LCS 260  // padded component-major stride (floats)

__global__ __launch_bounds__(256, 4) void k_scan(const float* __restrict__ path,
                                                 float* __restrict__ out,
                                                 float* __restrict__ sigA,
                                                 float* __restrict__ sigB) {
    const int bid = blockIdx.x;
    const int j = bid >> 4;
    const int a = bid & 15;
    const int tid = threadIdx.x;
    const int h = tid >> 7;          // time chunk: 0 -> [0,128), 1 -> [128,255)
    const int b = (tid >> 3) & 15;
    const int c0 = tid & 7;          // owns c0 and c0+8

    __shared__ float Lp[NL * NC];    // path -> (in-place) time-major diffs; reused in epilogue
    __shared__ float Lc[NC * LCS];   // component-major diffs [i][t], padded

    // stage path[j] (16 KB, coalesced)
    const float* pj = path + (size_t)j * NL * NC;
#pragma unroll
    for (int k = 0; k < 4; ++k) {
        const int f = tid + k * 256;
        *(float4*)&Lp[f * 4] = *(const float4*)&pj[f * 4];
    }
    __syncthreads();

    // diffs into registers, then in-place Lp (time-major) + Lc (component-major)
    float4 dif[4];
#pragma unroll
    for (int k = 0; k < 4; ++k) {
        const int f = tid + k * 256;  // float4 index
        if (f < 1020) {
            const float4 x0 = *(const float4*)&Lp[f * 4];
            const float4 x1 = *(const float4*)&Lp[f * 4 + 16];
            dif[k] = make_float4(x1.x - x0.x, x1.y - x0.y, x1.z - x0.z, x1.w - x0.w);
        }
    }
    __syncthreads();
#pragma unroll
    for (int k = 0; k < 4; ++k) {
        const int f = tid + k * 256;
        if (f < 1020) {
            *(float4*)&Lp[f * 4] = dif[k];
            const int t = f >> 2;            // time index
            const int i0 = 4 * (f & 3);      // component base
            Lc[(i0 + 0) * LCS + t] = dif[k].x;
            Lc[(i0 + 1) * LCS + t] = dif[k].y;
            Lc[(i0 + 2) * LCS + t] = dif[k].z;
            Lc[(i0 + 3) * LCS + t] = dif[k].w;
        }
    }
    __syncthreads();

    float s4a[16], s4b[16];
#pragma unroll
    for (int d = 0; d < 16; ++d) { s4a[d] = 0.f; s4b[d] = 0.f; }
    float s3_0 = 0.f, s3_1 = 0.f, s2ab = 0.f, s1a = 0.f;

    const int t0 = h ? 128 : 0;
    const int t1 = h ? NSTEP : 128;

    int t = t0;
    const int nv = (t1 - t0) >> 2;
    for (int it = 0; it < nv; ++it, t += 4) {
        const float4 va = *(const float4*)(Lc + a * LCS + t);         // broadcast
        const float4 vb = *(const float4*)(Lc + b * LCS + t);         // conflict-free
        const float4 vc0 = *(const float4*)(Lc + c0 * LCS + t);
        const float4 vc1 = *(const float4*)(Lc + (c0 + 8) * LCS + t);
#pragma unroll
        for (int u = 0; u < 4; ++u) {
            const float* r = Lp + (t + u) * NC;
            const float4 q0 = *(const float4*)(r);       // uniform b128 broadcast
            const float4 q1 = *(const float4*)(r + 4);
            const float4 q2 = *(const float4*)(r + 8);
            const float4 q3 = *(const float4*)(r + 12);
            const float dxa = (u == 0) ? va.x : (u == 1) ? va.y : (u == 2) ? va.z : va.w;
            const float dxb = (u == 0) ? vb.x : (u == 1) ? vb.y : (u == 2) ? vb.z : vb.w;
            const float dxc0 = (u == 0) ? vc0.x : (u == 1) ? vc0.y : (u == 2) ? vc0.z : vc0.w;
            const float dxc1 = (u == 0) ? vc1.x : (u == 1) ? vc1.y : (u == 2) ? vc1.z : vc1.w;

            const float P = dxb * s1a;
            const float Q = dxb * dxa;
            const float pre4 = fmaf(1.f / 6.f, P, fmaf(1.f / 24.f, Q, 0.5f * s2ab));
            const float U = fmaf(0.5f, P, fmaf(1.f / 6.f, Q, s2ab));
            const float T0 = fmaf(dxc0, pre4, s3_0);
            const float T1 = fmaf(dxc1, pre4, s3_1);
            const float dv[16] = {q0.x, q0.y, q0.z, q0.w, q1.x, q1.y, q1.z, q1.w,
                                  q2.x, q2.y, q2.z, q2.w, q3.x, q3.y, q3.z, q3.w};
#pragma unroll
            for (int d = 0; d < 16; ++d) {
                s4a[d] = fmaf(dv[d], T0, s4a[d]);
                s4b[d] = fmaf(dv[d], T1, s4b[d]);
            }
            s3_0 = fmaf(dxc0, U, s3_0);
            s3_1 = fmaf(dxc1, U, s3_1);
            s2ab = fmaf(dxb, fmaf(0.5f, dxa, s1a), s2ab);
            s1a += dxa;
        }
    }
    // tail (half 1 only: t = 252..254), scalar reads from time-major rows
    for (; t < t1; ++t) {
        const float* r = Lp + t * NC;
        const float4 q0 = *(const float4*)(r);
        const float4 q1 = *(const float4*)(r + 4);
        const float4 q2 = *(const float4*)(r + 8);
        const float4 q3 = *(const float4*)(r + 12);
        const float dxa = r[a];
        const float dxb = r[b];
        const float dxc0 = r[c0];
        const float dxc1 = r[c0 + 8];
        const float P = dxb * s1a;
        const float Q = dxb * dxa;
        const float pre4 = fmaf(1.f / 6.f, P, fmaf(1.f / 24.f, Q, 0.5f * s2ab));
        const float U = fmaf(0.5f, P, fmaf(1.f / 6.f, Q, s2ab));
        const float T0 = fmaf(dxc0, pre4, s3_0);
        const float T1 = fmaf(dxc1, pre4, s3_1);
        const float dv[16] = {q0.x, q0.y, q0.z, q0.w, q1.x, q1.y, q1.z, q1.w,
                              q2.x, q2.y, q2.z, q2.w, q3.x, q3.y, q3.z, q3.w};
#pragma unroll
        for (int d = 0; d < 16; ++d) {
            s4a[d] = fmaf(dv[d], T0, s4a[d]);
            s4b[d] = fmaf(dv[d], T1, s4b[d]);
        }
        s3_0 = fmaf(dxc0, U, s3_0);
        s3_1 = fmaf(dxc1, U, s3_1);
        s2ab = fmaf(dxb, fmaf(0.5f, dxa, s1a), s2ab);
        s1a += dxa;
    }

    // epilogue: merge A4 + B4 in LDS (both halves live in this block),
    // write ONE 16 KB slice (A4+B4) to out. Cross terms are k_log's job.
    __syncthreads();
    float* ls = Lp;  // reuse
    const int base = b * 256 + c0 * 16;
    if (h == 0) {
#pragma unroll
        for (int d = 0; d < 16; d += 4) {
            *(float4*)&ls[base + d] = make_float4(s4a[d], s4a[d + 1], s4a[d + 2], s4a[d + 3]);
            *(float4*)&ls[base + 128 + d] =
                make_float4(s4b[d], s4b[d + 1], s4b[d + 2], s4b[d + 3]);
        }
    }
    __syncthreads();
    if (h == 1) {
#pragma unroll
        for (int d = 0; d < 16; d += 4) {
            float4 v0 = *(const float4*)&ls[base + d];
            v0.x += s4a[d]; v0.y += s4a[d + 1]; v0.z += s4a[d + 2]; v0.w += s4a[d + 3];
            *(float4*)&ls[base + d] = v0;
            float4 v1 = *(const float4*)&ls[base + 128 + d];
            v1.x += s4b[d]; v1.y += s4b[d + 1]; v1.z += s4b[d + 2]; v1.w += s4b[d + 3];
            *(float4*)&ls[base + 128 + d] = v1;
        }
    }
    __syncthreads();
    {
        float* o4 = out + (size_t)j * OUTB + OFF_L4 + a * 4096;
#pragma unroll
        for (int k = 0; k < 4; ++k) {
            const int f = tid + k * 256;
            *(float4*)(o4 + f * 4) = *(const float4*)&ls[f * 4];
        }
    }

    // levels 1-3 of this thread's chunk
    float* sg = (h ? sigB : sigA) + (size_t)j * SIG123;
    sg[OFF_L3 + (a * 16 + b) * 16 + c0] = s3_0;
    sg[OFF_L3 + (a * 16 + b) * 16 + c0 + 8] = s3_1;
    if (c0 == 0) sg[OFF_L2 + a * 16 + b] = s2ab;
    if ((tid & 127) == 0) sg[a] = s1a;
}

// Chen cross-terms (S4 = [A4+B4] + A1(x)B3 + A2(x)B2 + A3(x)B1) + log
// correction. Block (j,a). Merged S1/S2/S3 in LDS (~20 KB); B3 from global
// (L2-resident, 17 KB per batch shared by 16 blocks).
__global__ __launch_bounds__(256) void k_log(const float* __restrict__ sigA,
                                             const float* __restrict__ sigB,
                                             float* __restrict__ out) {
    const int bid = blockIdx.x;
    const int j = bid >> 4;
    const int a = bid & 15;
    const int tid = threadIdx.x;
    const int q = tid >> 4;
    const int r = tid & 15;

    const float* A = sigA + (size_t)j * SIG123;
    const float* Bp = sigB + (size_t)j * SIG123;

    __shared__ float S1m[16], B1s[16], A2s[16];
    __shared__ float S2m[256], B2s[256], A3s[256];
    __shared__ float S3m[4096];

    const float b1r = Bp[r];             // B1[r]
    const float b2t = Bp[OFF_L2 + tid];  // B2[q,r]

    if (tid < 16) {
        const float bb = Bp[tid];
        B1s[tid] = bb;
        S1m[tid] = A[tid] + bb;               // S1 = A1 + B1
        A2s[tid] = A[OFF_L2 + a * 16 + tid];  // A2[a,:]
    }
    B2s[tid] = b2t;
    S2m[tid] = A[OFF_L2 + tid] + b2t + A[q] * b1r;  // S2 = A2 + B2 + A1(x)B1
    A3s[tid] = A[OFF_L3 + a * 256 + tid];           // A3[a,:,:]
#pragma unroll
    for (int k = 0; k < 16; ++k) {  // S3[p=k,q,r] = A3 + B3 + A1[p]B2[qr] + A2[pq]B1[r]
        const int m = k * 256 + tid;
        S3m[m] = A[OFF_L3 + m] + Bp[OFF_L3 + m] + A[k] * b2t + A[OFF_L2 + k * 16 + q] * b1r;
    }
    __syncthreads();

    const float s1a = S1m[a];
    const float A1a = A[a];
    float* outj = out + (size_t)j * OUTB;
    float* o4 = outj + OFF_L4 + a * 4096;
    const float Ac = -0.5f * s1a;

#pragma unroll
    for (int k = 0; k < 4; ++k) {
        const int f = tid + k * 256;
        const int m0 = f * 4;  // element offset: b*256 + c*16 + d0
        const int bb = m0 >> 8;
        const int cc = (m0 >> 4) & 15;
        const float s1b = S1m[bb], s1c = S1m[cc];
        const float s2ab = S2m[a * 16 + bb];
        const float s2bc = S2m[bb * 16 + cc];
        const float s3abc = S3m[a * 256 + (m0 >> 4)];  // merged S3[a,b,c]
        const float a3x = A3s[m0 >> 4];                // A3[a,b,c]
        const float a2x = A2s[bb];                     // A2[a,b]

        const float4 a4 = *(const float4*)(o4 + m0);              // A4+B4
        const float4 b3v = *(const float4*)(Bp + OFF_L3 + m0);    // B3[b,c,d..] (L2)
        const float4 b2v = *(const float4*)(&B2s[m0 & 255]);
        const float4 b1v = *(const float4*)(&B1s[m0 & 15]);
        const float4 v3 = *(const float4*)(&S3m[m0]);
        const float4 v2 = *(const float4*)(&S2m[m0 & 255]);
        const float4 v1 = *(const float4*)(&S1m[m0 & 15]);

        const float Bv = fmaf((1.f / 3.f) * s1a, s1b, -0.5f * s2ab);
        const float Cv = -0.5f * s3abc + (1.f / 3.f) * fmaf(s1a, s2bc, s2ab * s1c)
                         - 0.25f * s1a * s1b * s1c;
        float4 rr;
        // merged S4 = (A4+B4) + A1[a]B3[bcd] + A2[ab]B2[cd] + A3[abc]B1[d]
        rr.x = a4.x + fmaf(A1a, b3v.x, fmaf(a2x, b2v.x, a3x * b1v.x));
        rr.y = a4.y + fmaf(A1a, b3v.y, fmaf(a2x, b2v.y, a3x * b1v.y));
        rr.z = a4.z + fmaf(A1a, b3v.z, fmaf(a2x, b2v.z, a3x * b1v.z));
        rr.w = a4.w + fmaf(A1a, b3v.w, fmaf(a2x, b2v.w, a3x * b1v.w));
        // log correction
        rr.x = fmaf(Ac, v3.x, rr.x) + fmaf(Bv, v2.x, Cv * v1.x);
        rr.y = fmaf(Ac, v3.y, rr.y) + fmaf(Bv, v2.y, Cv * v1.y);
        rr.z = fmaf(Ac, v3.z, rr.z) + fmaf(Bv, v2.z, Cv * v1.z);
        rr.w = fmaf(Ac, v3.w, rr.w) + fmaf(Bv, v2.w, Cv * v1.w);
        *(float4*)(o4 + m0) = rr;
    }

    // level 3 (coalesced)
    {
        const float s1b = S1m[q], s1c = S1m[r];
        const float s2ab = S2m[a * 16 + q];
        const float s2bc = S2m[q * 16 + r];
        const float s3abc = S3m[a * 256 + tid];
        const float r3 = s3abc - 0.5f * fmaf(s1a, s2bc, s2ab * s1c)
                         + (1.f / 3.f) * s1a * s1b * s1c;
        outj[OFF_L3 + a * 256 + tid] = r3;
    }
    // level 2
    if (tid < 16) outj[OFF_L2 + a * 16 + tid] = fmaf(-0.5f * s1a, S1m[tid], S2m[a * 16 + tid]);
    // level 1
    if (tid == 0) outj[a] = s1a;
}

extern "C" void kernel_launch(void* const* d_in, const int* in_sizes, int n_in,
                              void* d_out, int out_size, void* d_ws, size_t ws_size,
                              hipStream_t stream) {
    const float* path = (const float*)d_in[0];
    float* out = (float*)d_out;
    float* ws = (float*)d_ws;
    float* sigA = ws + SIGA_OFF;
    float* sigB = ws + SIGB_OFF;

    k_scan<<<NB * 16, 256, 0, stream>>>(path, out, sigA, sigB);
    k_log<<<NB * 16, 256, 0, stream>>>(sigA, sigB, out);
}